// Round 20
// baseline (629.214 us; speedup 1.0000x reference)
//
#include <hip/hip_runtime.h>
#include <stdint.h>

#define NE 500000
#define NN 50000
#define ND 256
#define ED 128
#define GD 64
#define MAXDEG 64

typedef float f4v __attribute__((ext_vector_type(4)));
typedef float f16v __attribute__((ext_vector_type(16)));
typedef short s8v __attribute__((ext_vector_type(8)));
typedef short s4v __attribute__((ext_vector_type(4)));

static __device__ __forceinline__ short f2bf(float f) {
  union { float f; uint32_t u; } v; v.f = f;
  uint32_t r = v.u + 0x7FFFu + ((v.u >> 16) & 1u);
  return (short)(r >> 16);
}
static __device__ __forceinline__ float bf2f(uint32_t u) {
  union { uint32_t u; float f; } v; v.u = u << 16; return v.f;
}

// ---- async global->LDS DMA, 16B per lane ----
static __device__ __forceinline__ void gload_lds16(const void* g, void* l) {
  __builtin_amdgcn_global_load_lds(
      (const __attribute__((address_space(1))) unsigned int*)g,
      (__attribute__((address_space(3))) unsigned int*)l,
      16, 0, 0);
}

// ---- pack W[K][C] fp32 -> bf16, 16x16x32 A-frag order [ks32][c][kh4][j8] ----
static __device__ __forceinline__ void pack_one(const float* __restrict__ src,
                                                short* __restrict__ dst, int C, int idx) {
  int k = idx / C, c = idx - k * C;
  int ks = k >> 5, kh = (k >> 3) & 3, j = k & 7;
  dst[(((ks * C + c) * 4 + kh) << 3) + j] = f2bf(src[idx]);
}
// ---- pack W[K][C] fp32 -> bf16, 32x32x16 A-frag order [ks16][c][kh2][j8] ----
static __device__ __forceinline__ void pack32_one(const float* __restrict__ src,
                                                  short* __restrict__ dst, int C, int idx) {
  int k = idx / C, c = idx - k * C;
  int ks = k >> 4, kh = (k >> 3) & 1, j = k & 7;
  dst[(((ks * C + c) * 2 + kh) << 3) + j] = f2bf(src[idx]);
}

// =======================================================================
// Fused prep. elist-build first (atomic latency hides under cvt/pack).
// w1p/w2p in 32x32 pack (edge); w3p/w4p in 16x16 pack (node).
// =======================================================================
#define J5 500000    // build elist (first)
#define J0 3200000   // cvt: NN*ND/4 threads, 4 elems each
#define J1 196608    // w1p 384x512  (32-pack)
#define J2 65536     // w2p 512x128  (32-pack)
#define J3 458752    // w3p 448x1024 (16-pack)
#define J4 262144    // w4p 1024x256 (16-pack)
__global__ void prep_kernel(const float* __restrict__ x, short* __restrict__ xbf,
                            const float* __restrict__ W1, const float* __restrict__ W2,
                            const float* __restrict__ W3, const float* __restrict__ W4,
                            short* __restrict__ w1p, short* __restrict__ w2p,
                            short* __restrict__ w3p, short* __restrict__ w4p,
                            const int* __restrict__ ecol, unsigned int* __restrict__ cnt,
                            int* __restrict__ elist) {
  int idx = blockIdx.x * blockDim.x + threadIdx.x;
  if (idx < J5) {
    int c = ecol[idx];
    unsigned int slot = atomicAdd(&cnt[c], 1u);
    if (slot < MAXDEG) elist[c * MAXDEG + slot] = idx;
    return;
  }
  idx -= J5;
  if (idx < J0) {
    int i = idx * 4;
    const float4 v = *(const float4*)(x + i);
    s4v o; o[0] = f2bf(v.x); o[1] = f2bf(v.y); o[2] = f2bf(v.z); o[3] = f2bf(v.w);
    *(s4v*)(xbf + i) = o;
    return;
  }
  idx -= J0;
  if (idx < J1) { pack32_one(W1, w1p, 512, idx); return; }
  idx -= J1;
  if (idx < J2) { pack32_one(W2, w2p, 128, idx); return; }
  idx -= J2;
  if (idx < J3) { pack_one(W3, w3p, 1024, idx); return; }
  idx -= J3;
  if (idx < J4) { pack_one(W4, w4p, 256, idx); return; }
}

// =======================================================================
// gather-mean (R16-benched).
// =======================================================================
__global__ void agg_kernel(const unsigned short* __restrict__ ebuf,
                           const int* __restrict__ elist,
                           const unsigned int* __restrict__ cnt,
                           unsigned short* __restrict__ aggbf) {
  int tid = threadIdx.x;
  int lane = tid & 63;
  int node = blockIdx.x * 4 + (tid >> 6);
  if (node >= NN) return;
  unsigned int deg = cnt[node];
  unsigned int jend = deg < MAXDEG ? deg : MAXDEG;
  const int jg = lane >> 4;
  const int ch = lane & 15;
  float a[8] = {0.f, 0.f, 0.f, 0.f, 0.f, 0.f, 0.f, 0.f};
  const int* el = elist + (size_t)node * MAXDEG;
  for (unsigned int j = jg; j < jend; j += 4) {
    int eid = el[j];
    s8v v = *(const s8v*)(ebuf + (size_t)eid * ED + ch * 8);
    #pragma unroll
    for (int i = 0; i < 8; ++i) a[i] += bf2f((uint32_t)(uint16_t)v[i]);
  }
  #pragma unroll
  for (int d = 16; d < 64; d <<= 1) {
    #pragma unroll
    for (int i = 0; i < 8; ++i) a[i] += __shfl_xor(a[i], d);
  }
  if (jg == 0) {
    float rc = 1.0f / (deg > 0 ? (float)deg : 1.0f);
    s8v o;
    #pragma unroll
    for (int i = 0; i < 8; ++i) o[i] = f2bf(a[i] * rc);
    *(s8v*)(aggbf + (size_t)node * ED + ch * 8) = o;
  }
}

// =======================================================================
// Edge kernel: R18 staging/phases + 32x32x16 MFMA (17% faster matrix
// pipe, half the MFMA count, ~40% fewer LDS fragment reads).
// GEMM1: wave w -> c-tile w (32 cols of H1) x 4 e-tiles: acc1[4] f16v.
// GEMM2: wave -> one 32x32 tile (c-tile w&3, e-tile w>>2): acc2 f16v.
// C/D layout (guide-verified): col=lane&31, row=(reg&3)+8*(reg>>2)+4*(l>>5).
// Phases: stage X(DMA)+E | bar | GEMM1 | w<8 write h0->Hb | bar |
//   w>=8 write h1->Xb, all GEMM2-h0 | bar | GEMM2-h1 | direct stores.
// LESSONS FROZEN: (R9) no reg-held globals across MFMA; (R15) no per-lane
// row-gathers feeding MFMA; LDS staging = transaction shaping.
// =======================================================================
__launch_bounds__(1024, 4)
__global__ void edge_kernel(const short* __restrict__ xbf,
                            const float* __restrict__ edge_attr,
                            const short* __restrict__ w1p,
                            const float* __restrict__ b1,
                            const short* __restrict__ w2p,
                            const float* __restrict__ b2,
                            const int* __restrict__ erow,
                            unsigned short* __restrict__ ebuf) {
  __shared__ __align__(16) short smem[81920];       // 160KB
  char* const Xb = (char*)smem;                     // [128][256] bf16; later H1 half1
  char* const Eb = (char*)smem + 65536;             // [128][128] bf16
  char* const Hb = (char*)smem + 98304;             // H1 half0 [128][256], XOR swz
  const int tid = threadIdx.x;
  const int lane = tid & 63;
  const int w = tid >> 6;          // wave 0..15
  const int l31 = lane & 31;
  const int lg = lane >> 5;        // 0..1 (k-half group)
  const int e0 = blockIdx.x * 128;

  // ---- X: DMA xbf rows (1KB = 2 rows per inst, 4 insts per wave) ----
  {
    #pragma unroll
    for (int i = 0; i < 4; ++i) {
      int p = w * 4 + i;                     // row pair 0..63
      int row = 2 * p + (lane >> 5);
      int rid = erow[e0 + row];              // tail reads stay in eidx buffer
      int cg = (lane & 31) ^ (row & 7);      // source-swizzled octet
      gload_lds16(xbf + (size_t)rid * 256 + cg * 8, Xb + p * 1024);
    }
  }
  // ---- E: stage ea fp32 -> bf16, octet-swizzled (concurrent with DMA) ----
  #pragma unroll
  for (int it = 0; it < 2; ++it) {
    int id = tid + it * 1024;                // 2048 octets
    int row = id >> 4, oct = id & 15;
    s8v vals = {0, 0, 0, 0, 0, 0, 0, 0};
    if (e0 + row < NE) {
      const float* p = edge_attr + (size_t)(e0 + row) * ED + oct * 8;
      const float4 v0 = *(const float4*)(p);
      const float4 v1 = *(const float4*)(p + 4);
      vals[0] = f2bf(v0.x); vals[1] = f2bf(v0.y); vals[2] = f2bf(v0.z); vals[3] = f2bf(v0.w);
      vals[4] = f2bf(v1.x); vals[5] = f2bf(v1.y); vals[6] = f2bf(v1.z); vals[7] = f2bf(v1.w);
    }
    *(s8v*)(Eb + row * 256 + ((oct ^ (row & 7)) << 4)) = vals;
  }
  __syncthreads();   // barrier 1: DMA drained + E visible

  // ---- GEMM1 (swapped, 32x32x16): acc1[et], c-tile w, K=384 (24 ks) ----
  f16v acc1[4];
  #pragma unroll
  for (int et = 0; et < 4; ++et)
    #pragma unroll
    for (int r = 0; r < 16; ++r)
      acc1[et][r] = 0.f;

  for (int ks = 0; ks < 16; ++ks) {          // k<256 from X
    s8v wf = *(const s8v*)(w1p + (((ks * 512 + w * 32 + l31) * 2 + lg) << 3));
    #pragma unroll
    for (int et = 0; et < 4; ++et) {
      int row = et * 32 + l31;
      int byte = row * 512 + (((ks * 2 + lg) ^ (row & 7)) << 4);
      s8v hf = *(const s8v*)(Xb + byte);
      acc1[et] = __builtin_amdgcn_mfma_f32_32x32x16_bf16(wf, hf, acc1[et], 0, 0, 0);
    }
  }
  for (int ks = 16; ks < 24; ++ks) {         // k>=256 from E
    s8v wf = *(const s8v*)(w1p + (((ks * 512 + w * 32 + l31) * 2 + lg) << 3));
    #pragma unroll
    for (int et = 0; et < 4; ++et) {
      int row = et * 32 + l31;
      int byte = row * 256 + ((((ks - 16) * 2 + lg) ^ (row & 7)) << 4);
      s8v hf = *(const s8v*)(Eb + byte);
      acc1[et] = __builtin_amdgcn_mfma_f32_32x32x16_bf16(wf, hf, acc1[et], 0, 0, 0);
    }
  }

  // ---- H1 write: wave w's c-tile [32w,32w+32) -> half (w>>3), local
  //      col lc = (w&7)*32 + 8q + 4*lg + 0..3; row = et*32 + l31. ----
  // waves 0-7: write h0 -> Hb (fresh region, no pre-barrier)
  if (w < 8) {
    #pragma unroll
    for (int et = 0; et < 4; ++et) {
      int row = et * 32 + l31;
      #pragma unroll
      for (int q = 0; q < 4; ++q) {
        int cg = w * 32 + 8 * q + 4 * lg;             // global H1 col base
        const float4 bv = *(const float4*)(b1 + cg);
        s4v o;
        float v0 = acc1[et][4 * q + 0] + bv.x; o[0] = f2bf(v0 > 0.f ? v0 : 0.f);
        float v1 = acc1[et][4 * q + 1] + bv.y; o[1] = f2bf(v1 > 0.f ? v1 : 0.f);
        float v2 = acc1[et][4 * q + 2] + bv.z; o[2] = f2bf(v2 > 0.f ? v2 : 0.f);
        float v3 = acc1[et][4 * q + 3] + bv.w; o[3] = f2bf(v3 > 0.f ? v3 : 0.f);
        int byte = (row * 512 + cg * 2) ^ ((row & 7) << 4);
        *(s4v*)(Hb + byte) = o;
      }
    }
  }
  __syncthreads();   // barrier 2: GEMM1 X-reads done (Xb free) + h0 visible

  // ---- waves 8-15: write h1 -> Xb; then all waves GEMM2 on h0 ----
  if (w >= 8) {
    #pragma unroll
    for (int et = 0; et < 4; ++et) {
      int row = et * 32 + l31;
      #pragma unroll
      for (int q = 0; q < 4; ++q) {
        int cg = w * 32 + 8 * q + 4 * lg;             // global col (>=256)
        const float4 bv = *(const float4*)(b1 + cg);
        int lc = cg - 256;
        s4v o;
        float v0 = acc1[et][4 * q + 0] + bv.x; o[0] = f2bf(v0 > 0.f ? v0 : 0.f);
        float v1 = acc1[et][4 * q + 1] + bv.y; o[1] = f2bf(v1 > 0.f ? v1 : 0.f);
        float v2 = acc1[et][4 * q + 2] + bv.z; o[2] = f2bf(v2 > 0.f ? v2 : 0.f);
        float v3 = acc1[et][4 * q + 3] + bv.w; o[3] = f2bf(v3 > 0.f ? v3 : 0.f);
        int byte = (row * 512 + lc * 2) ^ ((row & 7) << 4);
        *(s4v*)(Xb + byte) = o;
      }
    }
  }

  // ---- GEMM2 (32x32x16): wave -> c-tile (w&3), e-tile (w>>2), K=512 ----
  f16v acc2;
  #pragma unroll
  for (int r = 0; r < 16; ++r) acc2[r] = 0.f;

  const int erow0 = (w >> 2) * 32;
  for (int ks = 0; ks < 16; ++ks) {          // K 0..255 from Hb
    s8v wf = *(const s8v*)(w2p + (((ks * 128 + (w & 3) * 32 + l31) * 2 + lg) << 3));
    int row = erow0 + l31;
    int byte = row * 512 + (((ks * 2 + lg) ^ (row & 7)) << 4);
    s8v hf = *(const s8v*)(Hb + byte);
    acc2 = __builtin_amdgcn_mfma_f32_32x32x16_bf16(wf, hf, acc2, 0, 0, 0);
  }
  __syncthreads();   // barrier 3: h1 visible

  for (int ks = 16; ks < 32; ++ks) {         // K 256..511 from Xb
    s8v wf = *(const s8v*)(w2p + (((ks * 128 + (w & 3) * 32 + l31) * 2 + lg) << 3));
    int row = erow0 + l31;
    int byte = row * 512 + ((((ks - 16) * 2 + lg) ^ (row & 7)) << 4);
    s8v hf = *(const s8v*)(Xb + byte);
    acc2 = __builtin_amdgcn_mfma_f32_32x32x16_bf16(wf, hf, acc2, 0, 0, 0);
  }

  // ---- epilogue: direct 8B stores; e = e0+erow0+l31, c = (w&3)*32+... ----
  {
    int e = e0 + erow0 + l31;
    if (e < NE) {
      #pragma unroll
      for (int q = 0; q < 4; ++q) {
        int c = (w & 3) * 32 + 8 * q + 4 * lg;
        const float4 bv = *(const float4*)(b2 + c);
        s4v o;
        o[0] = f2bf(acc2[4 * q + 0] + bv.x);
        o[1] = f2bf(acc2[4 * q + 1] + bv.y);
        o[2] = f2bf(acc2[4 * q + 2] + bv.z);
        o[3] = f2bf(acc2[4 * q + 3] + bv.w);
        *(s4v*)(ebuf + (size_t)e * ED + c) = o;
      }
    }
  }
}

// =======================================================================
// Node kernel: EXACT R18-benched version (16x16 MFMA, w3p/w4p 16-pack).
// =======================================================================
__launch_bounds__(1024, 4)
__global__ void node_kernel(const float* __restrict__ x,
                            const short* __restrict__ xbf,
                            const float* __restrict__ u,
                            const short* __restrict__ w3p,
                            const float* __restrict__ b3,
                            const short* __restrict__ w4p,
                            const float* __restrict__ b4,
                            const float* __restrict__ gamma,
                            const float* __restrict__ beta,
                            const int* __restrict__ batch,
                            const unsigned short* __restrict__ aggbf,
                            float* __restrict__ out) {
  __shared__ __align__(16) short smem[65536];       // 128KB
  char* const Xn = (char*)smem;                     // [64][256] bf16, 512B rows
  char* const An = (char*)smem + 32768;             // [64][128] bf16, 256B rows
  char* const Un = (char*)smem + 49152;             // [64][64]  bf16, 128B rows
  char* const H1r = (char*)smem;                    // H3 half1 (over stage)
  char* const H0r = (char*)smem + 65536;            // H3 half0
  const int tid = threadIdx.x;
  const int lane = tid & 63;
  const int w = tid >> 6;          // 0..15
  const int lh = lane >> 4;        // 0..3
  const int ll = lane & 15;        // 0..15
  const int n0 = blockIdx.x * 64;

  {
    #pragma unroll
    for (int i = 0; i < 2; ++i) {
      int p = w * 2 + i;                     // row pair 0..31
      int row = 2 * p + (lane >> 5);
      int node = n0 + row; if (node >= NN) node = NN - 1;
      int cg = (lane & 31) ^ (row & 7);
      gload_lds16(xbf + (size_t)node * 256 + cg * 8, Xn + p * 1024);
    }
  }
  {
    int row = tid >> 4, oct = tid & 15;
    s8v v = {0, 0, 0, 0, 0, 0, 0, 0};
    int node = n0 + row;
    if (node < NN) v = *(const s8v*)(aggbf + (size_t)node * ED + oct * 8);
    *(s8v*)(An + row * 256 + ((oct ^ (row & 7)) << 4)) = v;
  }
  if (tid < 512) {
    int row = tid >> 3, oct = tid & 7;
    s8v v = {0, 0, 0, 0, 0, 0, 0, 0};
    int node = n0 + row;
    if (node < NN) {
      const float* up = u + (size_t)batch[node] * GD + oct * 8;
      const float4 v0 = *(const float4*)(up);
      const float4 v1 = *(const float4*)(up + 4);
      v[0] = f2bf(v0.x); v[1] = f2bf(v0.y); v[2] = f2bf(v0.z); v[3] = f2bf(v0.w);
      v[4] = f2bf(v1.x); v[5] = f2bf(v1.y); v[6] = f2bf(v1.z); v[7] = f2bf(v1.w);
    }
    *(s8v*)(Un + row * 128 + ((oct ^ (row & 7)) << 4)) = v;
  }
  __syncthreads();   // barrier 1

  f4v acc3[4][4];
  #pragma unroll
  for (int n = 0; n < 4; ++n)
    #pragma unroll
    for (int m = 0; m < 4; ++m)
      acc3[n][m] = (f4v){0.f, 0.f, 0.f, 0.f};

  for (int ks = 0; ks < 14; ++ks) {
    s8v af[4];
    #pragma unroll
    for (int m = 0; m < 4; ++m) {
      int row = 16 * m + ll;
      int byte;
      if (ks < 8)       byte = row * 512 + (((ks * 4 + lh) ^ (row & 7)) << 4);
      else if (ks < 12) byte = row * 256 + ((((ks - 8) * 4 + lh) ^ (row & 7)) << 4);
      else              byte = row * 128 + ((((ks - 12) * 4 + lh) ^ (row & 7)) << 4);
      const char* base = (ks < 8) ? Xn : (ks < 12) ? An : Un;
      af[m] = *(const s8v*)(base + byte);
    }
    #pragma unroll
    for (int n = 0; n < 4; ++n) {
      s8v wf = *(const s8v*)(w3p + (((ks * 1024 + w * 64 + 16 * n + ll) * 4 + lh) << 3));
      #pragma unroll
      for (int m = 0; m < 4; ++m)
        acc3[n][m] = __builtin_amdgcn_mfma_f32_16x16x32_bf16(wf, af[m], acc3[n][m], 0, 0, 0);
    }
  }

  if (w < 8) {
    #pragma unroll
    for (int n = 0; n < 4; ++n) {
      int lc = w * 64 + 16 * n + 4 * lh;
      const float4 bv = *(const float4*)(b3 + lc);
      #pragma unroll
      for (int m = 0; m < 4; ++m) {
        int row = 16 * m + ll;
        s4v o;
        float v0 = acc3[n][m][0] + bv.x; o[0] = f2bf(v0 > 0.f ? v0 : 0.f);
        float v1 = acc3[n][m][1] + bv.y; o[1] = f2bf(v1 > 0.f ? v1 : 0.f);
        float v2 = acc3[n][m][2] + bv.z; o[2] = f2bf(v2 > 0.f ? v2 : 0.f);
        float v3 = acc3[n][m][3] + bv.w; o[3] = f2bf(v3 > 0.f ? v3 : 0.f);
        int byte = (row * 1024 + lc * 2) ^ ((row & 7) << 4);
        *(s4v*)(H0r + byte) = o;
      }
    }
  }
  __syncthreads();   // barrier 2

  if (w >= 8) {
    #pragma unroll
    for (int n = 0; n < 4; ++n) {
      int lc = (w - 8) * 64 + 16 * n + 4 * lh;
      const float4 bv = *(const float4*)(b3 + 512 + lc);
      #pragma unroll
      for (int m = 0; m < 4; ++m) {
        int row = 16 * m + ll;
        s4v o;
        float v0 = acc3[n][m][0] + bv.x; o[0] = f2bf(v0 > 0.f ? v0 : 0.f);
        float v1 = acc3[n][m][1] + bv.y; o[1] = f2bf(v1 > 0.f ? v1 : 0.f);
        float v2 = acc3[n][m][2] + bv.z; o[2] = f2bf(v2 > 0.f ? v2 : 0.f);
        float v3 = acc3[n][m][3] + bv.w; o[3] = f2bf(v3 > 0.f ? v3 : 0.f);
        int byte = (row * 1024 + lc * 2) ^ ((row & 7) << 4);
        *(s4v*)(H1r + byte) = o;
      }
    }
  }

  f4v acc4[4];
  #pragma unroll
  for (int m = 0; m < 4; ++m)
    acc4[m] = (f4v){0.f, 0.f, 0.f, 0.f};

  for (int ks = 0; ks < 16; ++ks) {
    s8v wf = *(const s8v*)(w4p + (((ks * 256 + w * 16 + ll) * 4 + lh) << 3));
    #pragma unroll
    for (int m = 0; m < 4; ++m) {
      int row = 16 * m + ll;
      int byte = (row * 1024 + ks * 64 + lh * 16) ^ ((row & 7) << 4);
      s8v hf = *(const s8v*)(H0r + byte);
      acc4[m] = __builtin_amdgcn_mfma_f32_16x16x32_bf16(wf, hf, acc4[m], 0, 0, 0);
    }
  }
  __syncthreads();   // barrier 3

  for (int ks = 16; ks < 32; ++ks) {
    s8v wf = *(const s8v*)(w4p + (((ks * 256 + w * 16 + ll) * 4 + lh) << 3));
    #pragma unroll
    for (int m = 0; m < 4; ++m) {
      int row = 16 * m + ll;
      int byte = (row * 1024 + (ks - 16) * 64 + lh * 16) ^ ((row & 7) << 4);
      s8v hf = *(const s8v*)(H1r + byte);
      acc4[m] = __builtin_amdgcn_mfma_f32_16x16x32_bf16(wf, hf, acc4[m], 0, 0, 0);
    }
  }
  __syncthreads();   // barrier 4

  float* yb = (float*)smem;
  {
    int cb = w * 16 + 4 * lh;
    const float4 bv = *(const float4*)(b4 + cb);
    #pragma unroll
    for (int m = 0; m < 4; ++m) {
      int row = 16 * m + ll;
      int node = n0 + row;
      float4 xv = {0.f, 0.f, 0.f, 0.f};
      if (node < NN) xv = *(const float4*)(x + (size_t)node * ND + cb);
      f4v o;
      o[0] = acc4[m][0] + bv.x + xv.x;
      o[1] = acc4[m][1] + bv.y + xv.y;
      o[2] = acc4[m][2] + bv.z + xv.z;
      o[3] = acc4[m][3] + bv.w + xv.w;
      *(f4v*)(yb + row * 260 + cb) = o;
    }
  }
  __syncthreads();   // barrier 5

  {
    int row = tid >> 4, sub = tid & 15;
    int node = n0 + row;
    float v[16];
    float sum = 0.f, ssq = 0.f;
    #pragma unroll
    for (int i = 0; i < 4; ++i) {
      const float4 t = *(const float4*)(yb + row * 260 + (i * 16 + sub) * 4);
      v[i * 4 + 0] = t.x; v[i * 4 + 1] = t.y; v[i * 4 + 2] = t.z; v[i * 4 + 3] = t.w;
      sum += t.x + t.y + t.z + t.w;
      ssq += t.x * t.x + t.y * t.y + t.z * t.z + t.w * t.w;
    }
    #pragma unroll
    for (int d = 1; d < 16; d <<= 1) {
      sum += __shfl_xor(sum, d);
      ssq += __shfl_xor(ssq, d);
    }
    float mu = sum * (1.f / 256.f);
    float var = ssq * (1.f / 256.f) - mu * mu;
    float rstd = rsqrtf(var + 1e-5f);
    if (node < NN) {
      #pragma unroll
      for (int i = 0; i < 4; ++i) {
        int c = (i * 16 + sub) * 4;
        const float4 g = *(const float4*)(gamma + c);
        const float4 be = *(const float4*)(beta + c);
        float4 o;
        o.x = (v[i * 4 + 0] - mu) * rstd * g.x + be.x;
        o.y = (v[i * 4 + 1] - mu) * rstd * g.y + be.y;
        o.z = (v[i * 4 + 2] - mu) * rstd * g.z + be.z;
        o.w = (v[i * 4 + 3] - mu) * rstd * g.w + be.w;
        *(float4*)(out + (size_t)node * ND + c) = o;
      }
    }
  }
}

extern "C" void kernel_launch(void* const* d_in, const int* in_sizes, int n_in,
                              void* d_out, int out_size, void* d_ws, size_t ws_size,
                              hipStream_t stream) {
  const float* x    = (const float*)d_in[0];
  const float* ea   = (const float*)d_in[1];
  const float* u    = (const float*)d_in[2];
  const float* W1   = (const float*)d_in[3];
  const float* b1   = (const float*)d_in[4];
  const float* W2   = (const float*)d_in[5];
  const float* b2   = (const float*)d_in[6];
  const float* W3   = (const float*)d_in[7];
  const float* b3   = (const float*)d_in[8];
  const float* W4   = (const float*)d_in[9];
  const float* b4   = (const float*)d_in[10];
  const float* gamma = (const float*)d_in[11];
  const float* beta  = (const float*)d_in[12];
  const int* eidx   = (const int*)d_in[13];
  const int* batch  = (const int*)d_in[14];
  float* out = (float*)d_out;

  char* p = (char*)d_ws;
  size_t off = 0;
  auto take = [&](size_t n) { char* r = p + off; off = (off + n + 255) & ~(size_t)255; return r; };
  short* xbf = (short*)take((size_t)NN * ND * 2);
  short* w1p = (short*)take((size_t)384 * 512 * 2);
  short* w2p = (short*)take((size_t)512 * 128 * 2);
  short* w3p = (short*)take((size_t)448 * 1024 * 2);
  short* w4p = (short*)take((size_t)1024 * 256 * 2);
  unsigned int* cnt = (unsigned int*)take((size_t)NN * 4);
  int* elist = (int*)take((size_t)NN * MAXDEG * 4);
  unsigned short* aggbf = (unsigned short*)take((size_t)NN * ED * 2);
  unsigned short* ebuf = (unsigned short*)take((size_t)NE * ED * 2);

  const int* erow = eidx;
  const int* ecol = eidx + NE;

  hipMemsetAsync(cnt, 0, (size_t)NN * 4, stream);
  {
    const int total = J5 + J0 + J1 + J2 + J3 + J4;
    prep_kernel<<<(total + 255) / 256, 256, 0, stream>>>(x, xbf, W1, W2, W3, W4,
                                                         w1p, w2p, w3p, w4p,
                                                         ecol, cnt, elist);
  }
  edge_kernel<<<(NE + 127) / 128, 1024, 0, stream>>>(xbf, ea, w1p, b1, w2p, b2, erow, ebuf);
  agg_kernel<<<(NN + 3) / 4, 256, 0, stream>>>(ebuf, elist, cnt, aggbf);
  node_kernel<<<(NN + 63) / 64, 1024, 0, stream>>>(x, xbf, u, w3p, b3, w4p, b4,
                                                   gamma, beta, batch, aggbf, out);
}

// Round 21
// 584.944 us; speedup vs baseline: 1.0757x; 1.0757x over previous
//
#include <hip/hip_runtime.h>
#include <stdint.h>

#define NE 500000
#define NN 50000
#define ND 256
#define ED 128
#define GD 64
#define MAXDEG 64

typedef float f4v __attribute__((ext_vector_type(4)));
typedef short s8v __attribute__((ext_vector_type(8)));
typedef short s4v __attribute__((ext_vector_type(4)));

static __device__ __forceinline__ short f2bf(float f) {
  union { float f; uint32_t u; } v; v.f = f;
  uint32_t r = v.u + 0x7FFFu + ((v.u >> 16) & 1u);
  return (short)(r >> 16);
}
static __device__ __forceinline__ float bf2f(uint32_t u) {
  union { uint32_t u; float f; } v; v.u = u << 16; return v.f;
}

// ---- async global->LDS DMA, 16B per lane ----
static __device__ __forceinline__ void gload_lds16(const void* g, void* l) {
  __builtin_amdgcn_global_load_lds(
      (const __attribute__((address_space(1))) unsigned int*)g,
      (__attribute__((address_space(3))) unsigned int*)l,
      16, 0, 0);
}

// ---- pack W[K][C] fp32 -> bf16 MFMA fragment order [ks][c][kh][j] ----
static __device__ __forceinline__ void pack_one(const float* __restrict__ src,
                                                short* __restrict__ dst, int C, int idx) {
  int k = idx / C, c = idx - k * C;
  int ks = k >> 5, kh = (k >> 3) & 3, j = k & 7;
  dst[(((ks * C + c) * 4 + kh) << 3) + j] = f2bf(src[idx]);
}

// =======================================================================
// Fused prep. elist-build first (atomic latency hides under cvt/pack).
// =======================================================================
#define J5 500000    // build elist (first)
#define J0 3200000   // cvt: NN*ND/4 threads, 4 elems each
#define J1 196608    // w1p 384x512
#define J2 65536     // w2p 512x128
#define J3 458752    // w3p 448x1024
#define J4 262144    // w4p 1024x256
__global__ void prep_kernel(const float* __restrict__ x, short* __restrict__ xbf,
                            const float* __restrict__ W1, const float* __restrict__ W2,
                            const float* __restrict__ W3, const float* __restrict__ W4,
                            short* __restrict__ w1p, short* __restrict__ w2p,
                            short* __restrict__ w3p, short* __restrict__ w4p,
                            const int* __restrict__ ecol, unsigned int* __restrict__ cnt,
                            int* __restrict__ elist) {
  int idx = blockIdx.x * blockDim.x + threadIdx.x;
  if (idx < J5) {
    int c = ecol[idx];
    unsigned int slot = atomicAdd(&cnt[c], 1u);
    if (slot < MAXDEG) elist[c * MAXDEG + slot] = idx;
    return;
  }
  idx -= J5;
  if (idx < J0) {
    int i = idx * 4;
    const float4 v = *(const float4*)(x + i);
    s4v o; o[0] = f2bf(v.x); o[1] = f2bf(v.y); o[2] = f2bf(v.z); o[3] = f2bf(v.w);
    *(s4v*)(xbf + i) = o;
    return;
  }
  idx -= J0;
  if (idx < J1) { pack_one(W1, w1p, 512, idx); return; }
  idx -= J1;
  if (idx < J2) { pack_one(W2, w2p, 128, idx); return; }
  idx -= J2;
  if (idx < J3) { pack_one(W3, w3p, 1024, idx); return; }
  idx -= J3;
  if (idx < J4) { pack_one(W4, w4p, 256, idx); return; }
}

// =======================================================================
// gather-mean (R16-benched): one wave per node, 4 edges/iter, 16B loads,
// shfl_xor(16,32) cross-group reduce.
// =======================================================================
__global__ void agg_kernel(const unsigned short* __restrict__ ebuf,
                           const int* __restrict__ elist,
                           const unsigned int* __restrict__ cnt,
                           unsigned short* __restrict__ aggbf) {
  int tid = threadIdx.x;
  int lane = tid & 63;
  int node = blockIdx.x * 4 + (tid >> 6);
  if (node >= NN) return;
  unsigned int deg = cnt[node];
  unsigned int jend = deg < MAXDEG ? deg : MAXDEG;
  const int jg = lane >> 4;        // 0..3
  const int ch = lane & 15;        // 16B chunk within row
  float a[8] = {0.f, 0.f, 0.f, 0.f, 0.f, 0.f, 0.f, 0.f};
  const int* el = elist + (size_t)node * MAXDEG;
  for (unsigned int j = jg; j < jend; j += 4) {
    int eid = el[j];
    s8v v = *(const s8v*)(ebuf + (size_t)eid * ED + ch * 8);
    #pragma unroll
    for (int i = 0; i < 8; ++i) a[i] += bf2f((uint32_t)(uint16_t)v[i]);
  }
  #pragma unroll
  for (int d = 16; d < 64; d <<= 1) {
    #pragma unroll
    for (int i = 0; i < 8; ++i) a[i] += __shfl_xor(a[i], d);
  }
  if (jg == 0) {
    float rc = 1.0f / (deg > 0 ? (float)deg : 1.0f);
    s8v o;
    #pragma unroll
    for (int i = 0; i < 8; ++i) o[i] = f2bf(a[i] * rc);
    *(s8v*)(aggbf + (size_t)node * ED + ch * 8) = o;
  }
}

// =======================================================================
// Edge kernel: R17/R18-benched best (388us, MfmaUtil 29.6, clean).
// stage X(DMA)+E(VALU) | bar | GEMM1 K=384 | write h0->Hb | bar |
// write h1->Xb | bar | GEMM2 K=512 | direct 8B stores.
// LESSONS FROZEN: (R9) no reg-held globals across MFMA (spill);
// (R15) no per-lane row-gathers feeding MFMA (uncoalesced);
// (R20) 32x32 MFMA loses to 16x16 here (acc-chain ILP 16->4/1, no LDS
// read savings); LDS staging = transaction shaping.
// =======================================================================
__launch_bounds__(1024, 4)
__global__ void edge_kernel(const short* __restrict__ xbf,
                            const float* __restrict__ edge_attr,
                            const short* __restrict__ w1p,
                            const float* __restrict__ b1,
                            const short* __restrict__ w2p,
                            const float* __restrict__ b2,
                            const int* __restrict__ erow,
                            unsigned short* __restrict__ ebuf) {
  __shared__ __align__(16) short smem[81920];       // 160KB
  char* const Xb = (char*)smem;                     // [128][256] bf16; later H1 half1
  char* const Eb = (char*)smem + 65536;             // [128][128] bf16
  char* const Hb = (char*)smem + 98304;             // H1 half0 [128][256], XOR swz
  const int tid = threadIdx.x;
  const int lane = tid & 63;
  const int w = tid >> 6;          // wave 0..15
  const int lh = lane >> 4;        // 0..3
  const int ll = lane & 15;        // 0..15
  const int e0 = blockIdx.x * 128;

  {
    #pragma unroll
    for (int i = 0; i < 4; ++i) {
      int p = w * 4 + i;                     // row pair 0..63
      int row = 2 * p + (lane >> 5);
      int rid = erow[e0 + row];              // tail reads stay in eidx buffer
      int cg = (lane & 31) ^ (row & 7);      // source-swizzled octet
      gload_lds16(xbf + (size_t)rid * 256 + cg * 8, Xb + p * 1024);
    }
  }

  #pragma unroll
  for (int it = 0; it < 2; ++it) {
    int id = tid + it * 1024;                // 2048 octets
    int row = id >> 4, oct = id & 15;
    s8v vals = {0, 0, 0, 0, 0, 0, 0, 0};
    if (e0 + row < NE) {
      const float* p = edge_attr + (size_t)(e0 + row) * ED + oct * 8;
      const float4 v0 = *(const float4*)(p);
      const float4 v1 = *(const float4*)(p + 4);
      vals[0] = f2bf(v0.x); vals[1] = f2bf(v0.y); vals[2] = f2bf(v0.z); vals[3] = f2bf(v0.w);
      vals[4] = f2bf(v1.x); vals[5] = f2bf(v1.y); vals[6] = f2bf(v1.z); vals[7] = f2bf(v1.w);
    }
    *(s8v*)(Eb + row * 256 + ((oct ^ (row & 7)) << 4)) = vals;
  }
  __syncthreads();   // barrier 1: DMA drained + E visible

  f4v acc1[2][8];
  #pragma unroll
  for (int n = 0; n < 2; ++n)
    #pragma unroll
    for (int m = 0; m < 8; ++m)
      acc1[n][m] = (f4v){0.f, 0.f, 0.f, 0.f};

  for (int ks = 0; ks < 8; ++ks) {
    s8v wf0 = *(const s8v*)(w1p + (((ks * 512 + w * 16 + ll) * 4 + lh) << 3));
    s8v wf1 = *(const s8v*)(w1p + (((ks * 512 + 256 + w * 16 + ll) * 4 + lh) << 3));
    #pragma unroll
    for (int mh = 0; mh < 2; ++mh) {
      s8v hf[4];
      #pragma unroll
      for (int m = 0; m < 4; ++m) {
        int row = 64 * mh + 16 * m + ll;
        int byte = row * 512 + (((ks * 4 + lh) ^ (row & 7)) << 4);
        hf[m] = *(const s8v*)(Xb + byte);
      }
      #pragma unroll
      for (int m = 0; m < 4; ++m) {
        acc1[0][4 * mh + m] = __builtin_amdgcn_mfma_f32_16x16x32_bf16(wf0, hf[m], acc1[0][4 * mh + m], 0, 0, 0);
        acc1[1][4 * mh + m] = __builtin_amdgcn_mfma_f32_16x16x32_bf16(wf1, hf[m], acc1[1][4 * mh + m], 0, 0, 0);
      }
    }
  }
  for (int ks = 8; ks < 12; ++ks) {
    s8v wf0 = *(const s8v*)(w1p + (((ks * 512 + w * 16 + ll) * 4 + lh) << 3));
    s8v wf1 = *(const s8v*)(w1p + (((ks * 512 + 256 + w * 16 + ll) * 4 + lh) << 3));
    #pragma unroll
    for (int mh = 0; mh < 2; ++mh) {
      s8v hf[4];
      #pragma unroll
      for (int m = 0; m < 4; ++m) {
        int row = 64 * mh + 16 * m + ll;
        int byte = row * 256 + ((((ks - 8) * 4 + lh) ^ (row & 7)) << 4);
        hf[m] = *(const s8v*)(Eb + byte);
      }
      #pragma unroll
      for (int m = 0; m < 4; ++m) {
        acc1[0][4 * mh + m] = __builtin_amdgcn_mfma_f32_16x16x32_bf16(wf0, hf[m], acc1[0][4 * mh + m], 0, 0, 0);
        acc1[1][4 * mh + m] = __builtin_amdgcn_mfma_f32_16x16x32_bf16(wf1, hf[m], acc1[1][4 * mh + m], 0, 0, 0);
      }
    }
  }

  // ---- write H1 half0 -> Hb (region fresh, no pre-barrier) ----
  {
    int lcb = w * 16 + 4 * lh;
    const float4 bv = *(const float4*)(b1 + lcb);
    #pragma unroll
    for (int m = 0; m < 8; ++m) {
      int row = 16 * m + ll;
      s4v o;
      float v0 = acc1[0][m][0] + bv.x; o[0] = f2bf(v0 > 0.f ? v0 : 0.f);
      float v1 = acc1[0][m][1] + bv.y; o[1] = f2bf(v1 > 0.f ? v1 : 0.f);
      float v2 = acc1[0][m][2] + bv.z; o[2] = f2bf(v2 > 0.f ? v2 : 0.f);
      float v3 = acc1[0][m][3] + bv.w; o[3] = f2bf(v3 > 0.f ? v3 : 0.f);
      int byte = (row * 512 + lcb * 2) ^ ((row & 7) << 4);
      *(s4v*)(Hb + byte) = o;
    }
  }
  __syncthreads();   // barrier 2: all GEMM1 X-reads done -> Xb reusable

  // ---- write H1 half1 -> Xb (X data dead) ----
  {
    int lcb = w * 16 + 4 * lh;
    const float4 bv = *(const float4*)(b1 + 256 + lcb);
    #pragma unroll
    for (int m = 0; m < 8; ++m) {
      int row = 16 * m + ll;
      s4v o;
      float v0 = acc1[1][m][0] + bv.x; o[0] = f2bf(v0 > 0.f ? v0 : 0.f);
      float v1 = acc1[1][m][1] + bv.y; o[1] = f2bf(v1 > 0.f ? v1 : 0.f);
      float v2 = acc1[1][m][2] + bv.z; o[2] = f2bf(v2 > 0.f ? v2 : 0.f);
      float v3 = acc1[1][m][3] + bv.w; o[3] = f2bf(v3 > 0.f ? v3 : 0.f);
      int byte = (row * 512 + lcb * 2) ^ ((row & 7) << 4);
      *(s4v*)(Xb + byte) = o;
    }
  }
  __syncthreads();   // barrier 3: full H1 visible

  f4v acc2[4];
  #pragma unroll
  for (int m = 0; m < 4; ++m)
    acc2[m] = (f4v){0.f, 0.f, 0.f, 0.f};

  for (int ks = 0; ks < 8; ++ks) {
    s8v wf = *(const s8v*)(w2p + (((ks * 128 + (w & 7) * 16 + ll) * 4 + lh) << 3));
    #pragma unroll
    for (int m = 0; m < 4; ++m) {
      int row = 64 * (w >> 3) + 16 * m + ll;
      int byte = (row * 512 + ks * 64 + lh * 16) ^ ((row & 7) << 4);
      s8v hf = *(const s8v*)(Hb + byte);
      acc2[m] = __builtin_amdgcn_mfma_f32_16x16x32_bf16(wf, hf, acc2[m], 0, 0, 0);
    }
  }
  for (int ks = 8; ks < 16; ++ks) {
    s8v wf = *(const s8v*)(w2p + (((ks * 128 + (w & 7) * 16 + ll) * 4 + lh) << 3));
    #pragma unroll
    for (int m = 0; m < 4; ++m) {
      int row = 64 * (w >> 3) + 16 * m + ll;
      int byte = (row * 512 + (ks - 8) * 64 + lh * 16) ^ ((row & 7) << 4);
      s8v hf = *(const s8v*)(Xb + byte);
      acc2[m] = __builtin_amdgcn_mfma_f32_16x16x32_bf16(wf, hf, acc2[m], 0, 0, 0);
    }
  }

  // ---- epilogue: direct 8B stores ----
  {
    int cb = (w & 7) * 16 + 4 * lh;
    const float4 bv = *(const float4*)(b2 + cb);
    #pragma unroll
    for (int m = 0; m < 4; ++m) {
      int row = 64 * (w >> 3) + 16 * m + ll;
      int e = e0 + row;
      if (e < NE) {
        s4v o;
        o[0] = f2bf(acc2[m][0] + bv.x);
        o[1] = f2bf(acc2[m][1] + bv.y);
        o[2] = f2bf(acc2[m][2] + bv.z);
        o[3] = f2bf(acc2[m][3] + bv.w);
        *(s4v*)(ebuf + (size_t)e * ED + cb) = o;
      }
    }
  }
}

// =======================================================================
// Node kernel: EXACT R18-benched version (total 583).
// =======================================================================
__launch_bounds__(1024, 4)
__global__ void node_kernel(const float* __restrict__ x,
                            const short* __restrict__ xbf,
                            const float* __restrict__ u,
                            const short* __restrict__ w3p,
                            const float* __restrict__ b3,
                            const short* __restrict__ w4p,
                            const float* __restrict__ b4,
                            const float* __restrict__ gamma,
                            const float* __restrict__ beta,
                            const int* __restrict__ batch,
                            const unsigned short* __restrict__ aggbf,
                            float* __restrict__ out) {
  __shared__ __align__(16) short smem[65536];       // 128KB
  char* const Xn = (char*)smem;                     // [64][256] bf16, 512B rows
  char* const An = (char*)smem + 32768;             // [64][128] bf16, 256B rows
  char* const Un = (char*)smem + 49152;             // [64][64]  bf16, 128B rows
  char* const H1r = (char*)smem;                    // H3 half1 (over stage)
  char* const H0r = (char*)smem + 65536;            // H3 half0
  const int tid = threadIdx.x;
  const int lane = tid & 63;
  const int w = tid >> 6;          // 0..15
  const int lh = lane >> 4;        // 0..3
  const int ll = lane & 15;        // 0..15
  const int n0 = blockIdx.x * 64;

  {
    #pragma unroll
    for (int i = 0; i < 2; ++i) {
      int p = w * 2 + i;                     // row pair 0..31
      int row = 2 * p + (lane >> 5);
      int node = n0 + row; if (node >= NN) node = NN - 1;
      int cg = (lane & 31) ^ (row & 7);
      gload_lds16(xbf + (size_t)node * 256 + cg * 8, Xn + p * 1024);
    }
  }
  {
    int row = tid >> 4, oct = tid & 15;
    s8v v = {0, 0, 0, 0, 0, 0, 0, 0};
    int node = n0 + row;
    if (node < NN) v = *(const s8v*)(aggbf + (size_t)node * ED + oct * 8);
    *(s8v*)(An + row * 256 + ((oct ^ (row & 7)) << 4)) = v;
  }
  if (tid < 512) {
    int row = tid >> 3, oct = tid & 7;
    s8v v = {0, 0, 0, 0, 0, 0, 0, 0};
    int node = n0 + row;
    if (node < NN) {
      const float* up = u + (size_t)batch[node] * GD + oct * 8;
      const float4 v0 = *(const float4*)(up);
      const float4 v1 = *(const float4*)(up + 4);
      v[0] = f2bf(v0.x); v[1] = f2bf(v0.y); v[2] = f2bf(v0.z); v[3] = f2bf(v0.w);
      v[4] = f2bf(v1.x); v[5] = f2bf(v1.y); v[6] = f2bf(v1.z); v[7] = f2bf(v1.w);
    }
    *(s8v*)(Un + row * 128 + ((oct ^ (row & 7)) << 4)) = v;
  }
  __syncthreads();   // barrier 1

  f4v acc3[4][4];
  #pragma unroll
  for (int n = 0; n < 4; ++n)
    #pragma unroll
    for (int m = 0; m < 4; ++m)
      acc3[n][m] = (f4v){0.f, 0.f, 0.f, 0.f};

  for (int ks = 0; ks < 14; ++ks) {
    s8v af[4];
    #pragma unroll
    for (int m = 0; m < 4; ++m) {
      int row = 16 * m + ll;
      int byte;
      if (ks < 8)       byte = row * 512 + (((ks * 4 + lh) ^ (row & 7)) << 4);
      else if (ks < 12) byte = row * 256 + ((((ks - 8) * 4 + lh) ^ (row & 7)) << 4);
      else              byte = row * 128 + ((((ks - 12) * 4 + lh) ^ (row & 7)) << 4);
      const char* base = (ks < 8) ? Xn : (ks < 12) ? An : Un;
      af[m] = *(const s8v*)(base + byte);
    }
    #pragma unroll
    for (int n = 0; n < 4; ++n) {
      s8v wf = *(const s8v*)(w3p + (((ks * 1024 + w * 64 + 16 * n + ll) * 4 + lh) << 3));
      #pragma unroll
      for (int m = 0; m < 4; ++m)
        acc3[n][m] = __builtin_amdgcn_mfma_f32_16x16x32_bf16(wf, af[m], acc3[n][m], 0, 0, 0);
    }
  }

  if (w < 8) {
    #pragma unroll
    for (int n = 0; n < 4; ++n) {
      int lc = w * 64 + 16 * n + 4 * lh;
      const float4 bv = *(const float4*)(b3 + lc);
      #pragma unroll
      for (int m = 0; m < 4; ++m) {
        int row = 16 * m + ll;
        s4v o;
        float v0 = acc3[n][m][0] + bv.x; o[0] = f2bf(v0 > 0.f ? v0 : 0.f);
        float v1 = acc3[n][m][1] + bv.y; o[1] = f2bf(v1 > 0.f ? v1 : 0.f);
        float v2 = acc3[n][m][2] + bv.z; o[2] = f2bf(v2 > 0.f ? v2 : 0.f);
        float v3 = acc3[n][m][3] + bv.w; o[3] = f2bf(v3 > 0.f ? v3 : 0.f);
        int byte = (row * 1024 + lc * 2) ^ ((row & 7) << 4);
        *(s4v*)(H0r + byte) = o;
      }
    }
  }
  __syncthreads();   // barrier 2

  if (w >= 8) {
    #pragma unroll
    for (int n = 0; n < 4; ++n) {
      int lc = (w - 8) * 64 + 16 * n + 4 * lh;
      const float4 bv = *(const float4*)(b3 + 512 + lc);
      #pragma unroll
      for (int m = 0; m < 4; ++m) {
        int row = 16 * m + ll;
        s4v o;
        float v0 = acc3[n][m][0] + bv.x; o[0] = f2bf(v0 > 0.f ? v0 : 0.f);
        float v1 = acc3[n][m][1] + bv.y; o[1] = f2bf(v1 > 0.f ? v1 : 0.f);
        float v2 = acc3[n][m][2] + bv.z; o[2] = f2bf(v2 > 0.f ? v2 : 0.f);
        float v3 = acc3[n][m][3] + bv.w; o[3] = f2bf(v3 > 0.f ? v3 : 0.f);
        int byte = (row * 1024 + lc * 2) ^ ((row & 7) << 4);
        *(s4v*)(H1r + byte) = o;
      }
    }
  }

  f4v acc4[4];
  #pragma unroll
  for (int m = 0; m < 4; ++m)
    acc4[m] = (f4v){0.f, 0.f, 0.f, 0.f};

  for (int ks = 0; ks < 16; ++ks) {
    s8v wf = *(const s8v*)(w4p + (((ks * 256 + w * 16 + ll) * 4 + lh) << 3));
    #pragma unroll
    for (int m = 0; m < 4; ++m) {
      int row = 16 * m + ll;
      int byte = (row * 1024 + ks * 64 + lh * 16) ^ ((row & 7) << 4);
      s8v hf = *(const s8v*)(H0r + byte);
      acc4[m] = __builtin_amdgcn_mfma_f32_16x16x32_bf16(wf, hf, acc4[m], 0, 0, 0);
    }
  }
  __syncthreads();   // barrier 3

  for (int ks = 16; ks < 32; ++ks) {
    s8v wf = *(const s8v*)(w4p + (((ks * 256 + w * 16 + ll) * 4 + lh) << 3));
    #pragma unroll
    for (int m = 0; m < 4; ++m) {
      int row = 16 * m + ll;
      int byte = (row * 1024 + (ks - 16) * 64 + lh * 16) ^ ((row & 7) << 4);
      s8v hf = *(const s8v*)(H1r + byte);
      acc4[m] = __builtin_amdgcn_mfma_f32_16x16x32_bf16(wf, hf, acc4[m], 0, 0, 0);
    }
  }
  __syncthreads();   // barrier 4

  float* yb = (float*)smem;
  {
    int cb = w * 16 + 4 * lh;
    const float4 bv = *(const float4*)(b4 + cb);
    #pragma unroll
    for (int m = 0; m < 4; ++m) {
      int row = 16 * m + ll;
      int node = n0 + row;
      float4 xv = {0.f, 0.f, 0.f, 0.f};
      if (node < NN) xv = *(const float4*)(x + (size_t)node * ND + cb);
      f4v o;
      o[0] = acc4[m][0] + bv.x + xv.x;
      o[1] = acc4[m][1] + bv.y + xv.y;
      o[2] = acc4[m][2] + bv.z + xv.z;
      o[3] = acc4[m][3] + bv.w + xv.w;
      *(f4v*)(yb + row * 260 + cb) = o;
    }
  }
  __syncthreads();   // barrier 5

  {
    int row = tid >> 4, sub = tid & 15;
    int node = n0 + row;
    float v[16];
    float sum = 0.f, ssq = 0.f;
    #pragma unroll
    for (int i = 0; i < 4; ++i) {
      const float4 t = *(const float4*)(yb + row * 260 + (i * 16 + sub) * 4);
      v[i * 4 + 0] = t.x; v[i * 4 + 1] = t.y; v[i * 4 + 2] = t.z; v[i * 4 + 3] = t.w;
      sum += t.x + t.y + t.z + t.w;
      ssq += t.x * t.x + t.y * t.y + t.z * t.z + t.w * t.w;
    }
    #pragma unroll
    for (int d = 1; d < 16; d <<= 1) {
      sum += __shfl_xor(sum, d);
      ssq += __shfl_xor(ssq, d);
    }
    float mu = sum * (1.f / 256.f);
    float var = ssq * (1.f / 256.f) - mu * mu;
    float rstd = rsqrtf(var + 1e-5f);
    if (node < NN) {
      #pragma unroll
      for (int i = 0; i < 4; ++i) {
        int c = (i * 16 + sub) * 4;
        const float4 g = *(const float4*)(gamma + c);
        const float4 be = *(const float4*)(beta + c);
        float4 o;
        o.x = (v[i * 4 + 0] - mu) * rstd * g.x + be.x;
        o.y = (v[i * 4 + 1] - mu) * rstd * g.y + be.y;
        o.z = (v[i * 4 + 2] - mu) * rstd * g.z + be.z;
        o.w = (v[i * 4 + 3] - mu) * rstd * g.w + be.w;
        *(float4*)(out + (size_t)node * ND + c) = o;
      }
    }
  }
}

extern "C" void kernel_launch(void* const* d_in, const int* in_sizes, int n_in,
                              void* d_out, int out_size, void* d_ws, size_t ws_size,
                              hipStream_t stream) {
  const float* x    = (const float*)d_in[0];
  const float* ea   = (const float*)d_in[1];
  const float* u    = (const float*)d_in[2];
  const float* W1   = (const float*)d_in[3];
  const float* b1   = (const float*)d_in[4];
  const float* W2   = (const float*)d_in[5];
  const float* b2   = (const float*)d_in[6];
  const float* W3   = (const float*)d_in[7];
  const float* b3   = (const float*)d_in[8];
  const float* W4   = (const float*)d_in[9];
  const float* b4   = (const float*)d_in[10];
  const float* gamma = (const float*)d_in[11];
  const float* beta  = (const float*)d_in[12];
  const int* eidx   = (const int*)d_in[13];
  const int* batch  = (const int*)d_in[14];
  float* out = (float*)d_out;

  char* p = (char*)d_ws;
  size_t off = 0;
  auto take = [&](size_t n) { char* r = p + off; off = (off + n + 255) & ~(size_t)255; return r; };
  short* xbf = (short*)take((size_t)NN * ND * 2);
  short* w1p = (short*)take((size_t)384 * 512 * 2);
  short* w2p = (short*)take((size_t)512 * 128 * 2);
  short* w3p = (short*)take((size_t)448 * 1024 * 2);
  short* w4p = (short*)take((size_t)1024 * 256 * 2);
  unsigned int* cnt = (unsigned int*)take((size_t)NN * 4);
  int* elist = (int*)take((size_t)NN * MAXDEG * 4);
  unsigned short* aggbf = (unsigned short*)take((size_t)NN * ED * 2);
  unsigned short* ebuf = (unsigned short*)take((size_t)NE * ED * 2);

  const int* erow = eidx;
  const int* ecol = eidx + NE;

  hipMemsetAsync(cnt, 0, (size_t)NN * 4, stream);
  {
    const int total = J5 + J0 + J1 + J2 + J3 + J4;
    prep_kernel<<<(total + 255) / 256, 256, 0, stream>>>(x, xbf, W1, W2, W3, W4,
                                                         w1p, w2p, w3p, w4p,
                                                         ecol, cnt, elist);
  }
  edge_kernel<<<(NE + 127) / 128, 1024, 0, stream>>>(xbf, ea, w1p, b1, w2p, b2, erow, ebuf);
  agg_kernel<<<(NN + 3) / 4, 256, 0, stream>>>(ebuf, elist, cnt, aggbf);
  node_kernel<<<(NN + 63) / 64, 1024, 0, stream>>>(x, xbf, u, w3p, b3, w4p, b4,
                                                   gamma, beta, batch, aggbf, out);
}